// Round 3
// 349.235 us; speedup vs baseline: 1.2659x; 1.2659x over previous
//
#include <hip/hip_runtime.h>

#define E 1024
#define KK 20
#define NOUT 40980      // KK*(2*E+1)
#define VLOC 20500      // KK + KK*E
#define SROW (2*NOUT)   // 81960
#define NPAIR 190       // K*(K-1)/2

// ws layout (floats): [0 .. 2B)           gram |G| per (b,which) block partials
//                     [2B .. 2B + 128B)   main num/den per-block partials (B*64 blocks * 2)
// No atomics, no init pass needed: every slot is written unconditionally.

// ---------------- Gram: one block per (b, which); full e-range; fused abs+reduce ----------------
__global__ __launch_bounds__(256) void gram_kernel(const float* __restrict__ nn,
                                                   float* __restrict__ ws) {
    __shared__ float2 sM[128 * 21];   // 128 e-rows, 20 k padded to 21 float2
    __shared__ float red[4];
    int bw = blockIdx.x, b = bw >> 1, which = bw & 1;
    const float* baseR = nn + (size_t)b * SROW + (which ? VLOC : KK);
    const float* baseI = baseR + NOUT;
    int t = threadIdx.x;
    int j = 0, kq = 1;
    if (t < NPAIR) {
        int p = t, cnt = KK - 1;
        while (p >= cnt) { p -= cnt; j++; cnt--; }
        kq = j + 1 + p;
    }
    float gr = 0.f, gi = 0.f;
    // register-prefetch pipeline over 8 chunks of 128 e-rows (2560 floats each)
    float rR[10], rI[10];
    #pragma unroll
    for (int i = 0; i < 10; i++) { int idx = t + i * 256; rR[i] = baseR[idx]; rI[i] = baseI[idx]; }
    for (int c = 0; c < 8; c++) {
        #pragma unroll
        for (int i = 0; i < 10; i++) {
            int idx = t + i * 256;
            sM[idx + idx / KK] = make_float2(rR[i], rI[i]);   // pad row 20 -> 21
        }
        __syncthreads();
        if (c < 7) {   // issue next chunk's global loads; latency hides under compute
            const float* nR = baseR + (c + 1) * 2560;
            const float* nI = baseI + (c + 1) * 2560;
            #pragma unroll
            for (int i = 0; i < 10; i++) { int idx = t + i * 256; rR[i] = nR[idx]; rI[i] = nI[idx]; }
        }
        if (t < NPAIR) {
            #pragma unroll 8
            for (int e = 0; e < 128; e++) {
                float2 a = sM[e * 21 + j];
                float2 cc = sM[e * 21 + kq];
                gr += a.x * cc.x - a.y * cc.y;     // plain product (no conj) per reference
                gi += a.x * cc.y + a.y * cc.x;
            }
        }
        __syncthreads();
    }
    float m = (t < NPAIR) ? sqrtf(gr * gr + gi * gi) : 0.f;
    #pragma unroll
    for (int off = 32; off > 0; off >>= 1) m += __shfl_down(m, off, 64);
    if ((t & 63) == 0) red[t >> 6] = m;
    __syncthreads();
    if (t == 0) ws[bw] = red[0] + red[1] + red[2] + red[3];
}

// ---------------- main: grid (8,8,B), 128x128 tile, 8x8 complex per thread ----------------
// K staged in two halves of 10 -> LDS 20.5 KB -> 2 blocks/CU; inner loop is VALU-bound
// (0.5 B LDS per FMA vs the 4x4 tile's 1.0 B/FMA which was LDS-BW-bound).
__global__ __launch_bounds__(256) void main_kernel(const float* __restrict__ nn,
                                                   const float* __restrict__ krn_r,
                                                   const float* __restrict__ krn_i,
                                                   float* __restrict__ ws) {
    __shared__ float2 sW[10 * 128];   // [k][e]  W = U*d, stride-1 writes, broadcast reads
    __shared__ float2 sV[10 * 128];   // [k][f]
    __shared__ float redN[4], redD[4];
    int b = blockIdx.z;
    int e0 = blockIdx.y * 128;
    int f0 = blockIdx.x * 128;
    const float* nb = nn + (size_t)b * SROW;
    int t = threadIdx.x;
    int fe = (t & 15) * 8;
    int te = (t >> 4) * 8;

    float pr[8][8], pi[8][8];
    #pragma unroll
    for (int i = 0; i < 8; i++)
        #pragma unroll
        for (int q = 0; q < 8; q++) { pr[i][q] = 0.f; pi[i][q] = 0.f; }

    #pragma unroll 1
    for (int h = 0; h < 2; h++) {
        int k0 = h * 10;
        if (h) __syncthreads();   // previous compute done before overwriting buffers
        // stage 10 k-rows of W and V; float2 loads along k (k0, 2*kp all even -> 8B aligned)
        for (int idx = t; idx < 640; idx += 256) {
            int e = idx & 127, kp = idx >> 7;       // kp wave-uniform -> scalar d loads
            int k = k0 + kp * 2;
            const float* pu = nb + KK + (size_t)(e0 + e) * KK + k;
            float2 ur = *(const float2*)pu;
            float2 ui = *(const float2*)(pu + NOUT);
            const float* pv = nb + VLOC + (size_t)(f0 + e) * KK + k;
            float2 vr = *(const float2*)pv;
            float2 vi = *(const float2*)(pv + NOUT);
            float dr0 = nb[k], di0 = nb[NOUT + k];
            float dr1 = nb[k + 1], di1 = nb[NOUT + k + 1];
            sW[(kp * 2) * 128 + e]     = make_float2(ur.x * dr0 - ui.x * di0, ur.x * di0 + ui.x * dr0);
            sW[(kp * 2 + 1) * 128 + e] = make_float2(ur.y * dr1 - ui.y * di1, ur.y * di1 + ui.y * dr1);
            sV[(kp * 2) * 128 + e]     = make_float2(vr.x, vi.x);
            sV[(kp * 2 + 1) * 128 + e] = make_float2(vr.y, vi.y);
        }
        __syncthreads();
        #pragma unroll 2
        for (int k = 0; k < 10; k++) {
            const float4* wp = (const float4*)(sW + k * 128 + te);   // 16 lanes same addr: broadcast
            const float4* vp = (const float4*)(sV + k * 128 + fe);   // contiguous: conflict-free
            float4 wA = wp[0], wB = wp[1], wC = wp[2], wD = wp[3];
            float4 vA = vp[0], vB = vp[1], vC = vp[2], vD = vp[3];
            float2 w[8] = {{wA.x,wA.y},{wA.z,wA.w},{wB.x,wB.y},{wB.z,wB.w},
                           {wC.x,wC.y},{wC.z,wC.w},{wD.x,wD.y},{wD.z,wD.w}};
            float2 v[8] = {{vA.x,vA.y},{vA.z,vA.w},{vB.x,vB.y},{vB.z,vB.w},
                           {vC.x,vC.y},{vC.z,vC.w},{vD.x,vD.y},{vD.z,vD.w}};
            #pragma unroll
            for (int i = 0; i < 8; i++)
                #pragma unroll
                for (int q = 0; q < 8; q++) {
                    pr[i][q] += w[i].x * v[q].x - w[i].y * v[q].y;
                    pi[i][q] += w[i].x * v[q].y + w[i].y * v[q].x;
                }
        }
    }

    // epilogue: stream kern tile row by row (keeps T out of registers during the k-loop)
    float num = 0.f, den = 0.f;
    size_t base = ((size_t)b * E + (size_t)(e0 + te)) * E + (size_t)(f0 + fe);
    #pragma unroll
    for (int i = 0; i < 8; i++) {
        const float* rp = krn_r + base + (size_t)i * E;
        const float* qp = krn_i + base + (size_t)i * E;
        float4 r0 = *(const float4*)rp;
        float4 r1 = *(const float4*)(rp + 4);
        float4 q0 = *(const float4*)qp;
        float4 q1 = *(const float4*)(qp + 4);
        float rr[8] = {r0.x,r0.y,r0.z,r0.w,r1.x,r1.y,r1.z,r1.w};
        float qq[8] = {q0.x,q0.y,q0.z,q0.w,q1.x,q1.y,q1.z,q1.w};
        #pragma unroll
        for (int q = 0; q < 8; q++) {
            float dr = rr[q] - pr[i][q];
            float di = qq[q] - pi[i][q];
            num += dr * dr + di * di;
            den += rr[q] * rr[q] + qq[q] * qq[q];
        }
    }
    #pragma unroll
    for (int off = 32; off > 0; off >>= 1) {
        num += __shfl_down(num, off, 64);
        den += __shfl_down(den, off, 64);
    }
    if ((t & 63) == 0) { redN[t >> 6] = num; redD[t >> 6] = den; }
    __syncthreads();
    if (t == 0) {
        int bid = ((int)blockIdx.z * 8 + (int)blockIdx.y) * 8 + (int)blockIdx.x;
        int moff = (int)gridDim.z * 2 + bid * 2;
        ws[moff]     = redN[0] + redN[1] + redN[2] + redN[3];
        ws[moff + 1] = redD[0] + redD[1] + redD[2] + redD[3];
    }
}

// ---------------- final reduce: one block sums all partials ----------------
__global__ __launch_bounds__(256) void fin_kernel(const float* __restrict__ ws,
                                                  const int* __restrict__ bsz,
                                                  float* __restrict__ out, int B) {
    __shared__ float acc[16];
    int t = threadIdx.x;
    float num = 0.f, den = 0.f, sU = 0.f, sV = 0.f;
    int moff = B * 2;
    int nmain = B * 64;
    for (int i = t; i < nmain; i += 256) {
        num += ws[moff + 2 * i];
        den += ws[moff + 2 * i + 1];
    }
    for (int i = t; i < B * 2; i += 256) {
        float g = ws[i];
        if (i & 1) sV += g; else sU += g;
    }
    #pragma unroll
    for (int off = 32; off > 0; off >>= 1) {
        num += __shfl_down(num, off, 64);
        den += __shfl_down(den, off, 64);
        sU  += __shfl_down(sU, off, 64);
        sV  += __shfl_down(sV, off, 64);
    }
    if ((t & 63) == 0) {
        int w = t >> 6;
        acc[w * 4 + 0] = num; acc[w * 4 + 1] = den;
        acc[w * 4 + 2] = sU;  acc[w * 4 + 3] = sV;
    }
    __syncthreads();
    if (t == 0) {
        num = acc[0] + acc[4] + acc[8]  + acc[12];
        den = acc[1] + acc[5] + acc[9]  + acc[13];
        sU  = acc[2] + acc[6] + acc[10] + acc[14];
        sV  = acc[3] + acc[7] + acc[11] + acc[15];
        float Bf = (float)bsz[0];
        float o1 = sU / Bf, o2 = sV / Bf;
        out[0] = num / den + 0.01f * (o1 + o2);
        out[1] = o1;
        out[2] = o2;
    }
}

extern "C" void kernel_launch(void* const* d_in, const int* in_sizes, int n_in,
                              void* d_out, int out_size, void* d_ws, size_t ws_size,
                              hipStream_t stream) {
    const float* nn = (const float*)d_in[0];
    const float* kr = (const float*)d_in[1];
    const float* ki = (const float*)d_in[2];
    const int* bsz = (const int*)d_in[3];
    float* ws = (float*)d_ws;
    float* out = (float*)d_out;
    int B = in_sizes[0] / SROW;

    hipLaunchKernelGGL(gram_kernel, dim3(B * 2), dim3(256), 0, stream, nn, ws);
    hipLaunchKernelGGL(main_kernel, dim3(E / 128, E / 128, B), dim3(256), 0, stream,
                       nn, kr, ki, ws);
    hipLaunchKernelGGL(fin_kernel, dim3(1), dim3(256), 0, stream, ws, bsz, out, B);
}

// Round 4
// 337.987 us; speedup vs baseline: 1.3080x; 1.0333x over previous
//
#include <hip/hip_runtime.h>

#define E 1024
#define KK 20
#define NOUT 40980      // KK*(2*E+1)
#define VLOC 20500      // KK + KK*E
#define SROW (2*NOUT)   // 81960
#define NPAIR 190       // K*(K-1)/2

// ws layout (floats): [0 .. 2B)           gram |G| per (b,which) block partials
//                     [2B .. 2B+2*B*64)   main num/den per-block partials
// No atomics, no init pass needed: every slot is written unconditionally.

// ---------------- Gram: one block per (b, which); full e-range; fused abs+reduce ----------------
__global__ __launch_bounds__(256) void gram_kernel(const float* __restrict__ nn,
                                                   float* __restrict__ ws) {
    __shared__ float2 sM[128 * 21];   // 128 e-rows, 20 k padded to 21 float2
    __shared__ float red[4];
    int bw = blockIdx.x, b = bw >> 1, which = bw & 1;
    const float* baseR = nn + (size_t)b * SROW + (which ? VLOC : KK);
    const float* baseI = baseR + NOUT;
    int t = threadIdx.x;
    int j = 0, kq = 1;
    if (t < NPAIR) {
        int p = t, cnt = KK - 1;
        while (p >= cnt) { p -= cnt; j++; cnt--; }
        kq = j + 1 + p;
    }
    float gr = 0.f, gi = 0.f;
    // register-prefetch pipeline over 8 chunks of 128 e-rows (2560 floats each)
    float rR[10], rI[10];
    #pragma unroll
    for (int i = 0; i < 10; i++) { int idx = t + i * 256; rR[i] = baseR[idx]; rI[i] = baseI[idx]; }
    for (int c = 0; c < 8; c++) {
        #pragma unroll
        for (int i = 0; i < 10; i++) {
            int idx = t + i * 256;
            sM[idx + idx / KK] = make_float2(rR[i], rI[i]);   // pad row 20 -> 21
        }
        __syncthreads();
        if (c < 7) {   // issue next chunk's global loads; latency hides under compute
            const float* nR = baseR + (c + 1) * 2560;
            const float* nI = baseI + (c + 1) * 2560;
            #pragma unroll
            for (int i = 0; i < 10; i++) { int idx = t + i * 256; rR[i] = nR[idx]; rI[i] = nI[idx]; }
        }
        if (t < NPAIR) {
            #pragma unroll 8
            for (int e = 0; e < 128; e++) {
                float2 a = sM[e * 21 + j];
                float2 cc = sM[e * 21 + kq];
                gr += a.x * cc.x - a.y * cc.y;     // plain product (no conj) per reference
                gi += a.x * cc.y + a.y * cc.x;
            }
        }
        __syncthreads();
    }
    float m = (t < NPAIR) ? sqrtf(gr * gr + gi * gi) : 0.f;
    #pragma unroll
    for (int off = 32; off > 0; off >>= 1) m += __shfl_down(m, off, 64);
    if ((t & 63) == 0) red[t >> 6] = m;
    __syncthreads();
    if (t == 0) ws[bw] = red[0] + red[1] + red[2] + red[3];
}

// ---------------- main: grid (8,8,B), 128x128 tile, 8x8 complex per thread ----------------
// Single-phase staging of all 20 k (one barrier). sV is XOR-swizzled at float4
// granularity so the 16-lane slice read hits all 8 bank groups (2-way = free)
// instead of 2 groups (8-way). Epilogue pipelines kern-row loads 2 rows ahead.
__global__ __launch_bounds__(256) void main_kernel(const float* __restrict__ nn,
                                                   const float* __restrict__ krn_r,
                                                   const float* __restrict__ krn_i,
                                                   float* __restrict__ ws) {
    __shared__ float2 sW[KK * 128];   // [k][e]  W = U*d, broadcast-style reads (2-way max)
    __shared__ float2 sV[KK * 128];   // [k][f]  XOR-swizzled
    __shared__ float redN[4], redD[4];
    int b = blockIdx.z;
    int e0 = blockIdx.y * 128;
    int f0 = blockIdx.x * 128;
    const float* nb = nn + (size_t)b * SROW;
    int t = threadIdx.x;
    int fe = (t & 15) * 8;            // this thread's f-slice (float2 units)
    int te = (t >> 4) * 8;            // this thread's e-slice

    // Swizzled read offsets for the 4 V float4-reads: F = 4*(t&15)+c, F' = F^((F>>3)&7)
    int i4 = (t & 15) * 4;
    int voff0, voff1, voff2, voff3;
    { int F, Fs;
      F = i4 + 0; Fs = F ^ ((F >> 3) & 7); voff0 = Fs << 1;
      F = i4 + 1; Fs = F ^ ((F >> 3) & 7); voff1 = Fs << 1;
      F = i4 + 2; Fs = F ^ ((F >> 3) & 7); voff2 = Fs << 1;
      F = i4 + 3; Fs = F ^ ((F >> 3) & 7); voff3 = Fs << 1; }

    // ---- stage all 20 k rows: W = U*d (unswizzled) and V (swizzled) ----
    for (int idx = t; idx < 1280; idx += 256) {
        int e = idx & 127, kp = idx >> 7;        // kp wave-uniform -> scalar d loads
        int k = kp * 2;
        const float* pu = nb + KK + (size_t)(e0 + e) * KK + k;
        float2 ur = *(const float2*)pu;
        float2 ui = *(const float2*)(pu + NOUT);
        const float* pv = nb + VLOC + (size_t)(f0 + e) * KK + k;
        float2 vr = *(const float2*)pv;
        float2 vi = *(const float2*)(pv + NOUT);
        float dr0 = nb[k], di0 = nb[NOUT + k];
        float dr1 = nb[k + 1], di1 = nb[NOUT + k + 1];
        int F = e >> 1;
        int es = ((F ^ ((F >> 3) & 7)) << 1) | (e & 1);   // swizzled float2 index
        sW[k * 128 + e]        = make_float2(ur.x * dr0 - ui.x * di0, ur.x * di0 + ui.x * dr0);
        sW[(k + 1) * 128 + e]  = make_float2(ur.y * dr1 - ui.y * di1, ur.y * di1 + ui.y * dr1);
        sV[k * 128 + es]       = make_float2(vr.x, vi.x);
        sV[(k + 1) * 128 + es] = make_float2(vr.y, vi.y);
    }
    __syncthreads();

    float pr[8][8], pi[8][8];
    #pragma unroll
    for (int i = 0; i < 8; i++)
        #pragma unroll
        for (int q = 0; q < 8; q++) { pr[i][q] = 0.f; pi[i][q] = 0.f; }

#define KSTEP(k) { \
        const float2* sWr = sW + (k) * 128; \
        const float2* sVr = sV + (k) * 128; \
        float4 wA = *(const float4*)(sWr + te);     \
        float4 wB = *(const float4*)(sWr + te + 2); \
        float4 wC = *(const float4*)(sWr + te + 4); \
        float4 wD = *(const float4*)(sWr + te + 6); \
        float4 vA = *(const float4*)(sVr + voff0);  \
        float4 vB = *(const float4*)(sVr + voff1);  \
        float4 vC = *(const float4*)(sVr + voff2);  \
        float4 vD = *(const float4*)(sVr + voff3);  \
        float2 w[8] = {{wA.x,wA.y},{wA.z,wA.w},{wB.x,wB.y},{wB.z,wB.w}, \
                       {wC.x,wC.y},{wC.z,wC.w},{wD.x,wD.y},{wD.z,wD.w}}; \
        float2 v[8] = {{vA.x,vA.y},{vA.z,vA.w},{vB.x,vB.y},{vB.z,vB.w}, \
                       {vC.x,vC.y},{vC.z,vC.w},{vD.x,vD.y},{vD.z,vD.w}}; \
        _Pragma("unroll") \
        for (int i = 0; i < 8; i++) \
            _Pragma("unroll") \
            for (int q = 0; q < 8; q++) { \
                pr[i][q] += w[i].x * v[q].x - w[i].y * v[q].y; \
                pi[i][q] += w[i].x * v[q].y + w[i].y * v[q].x; \
            } }

    #pragma unroll 2
    for (int k = 0; k < 10; k++) KSTEP(k)

    // prefetch kern rows 0,1 here: ~10 k-steps of compute hide the HBM latency
    size_t base = ((size_t)b * E + (size_t)(e0 + te)) * E + (size_t)(f0 + fe);
    const float* rp = krn_r + base;
    const float* qp = krn_i + base;
#define LDROW(R0,R1,Q0,Q1,I) { \
        const float* _r = rp + (size_t)(I) * E; \
        const float* _q = qp + (size_t)(I) * E; \
        R0 = *(const float4*)_r;  R1 = *(const float4*)(_r + 4); \
        Q0 = *(const float4*)_q;  Q1 = *(const float4*)(_q + 4); }
    float4 Ar0, Ar1, Aq0, Aq1, Br0, Br1, Bq0, Bq1;
    float4 Cr0, Cr1, Cq0, Cq1, Dr0, Dr1, Dq0, Dq1;
    LDROW(Ar0, Ar1, Aq0, Aq1, 0)
    LDROW(Br0, Br1, Bq0, Bq1, 1)

    #pragma unroll 2
    for (int k = 10; k < 20; k++) KSTEP(k)

    float num = 0.f, den = 0.f;
#define CONS(R0,R1,Q0,Q1,I) { \
        float rr[8] = {R0.x,R0.y,R0.z,R0.w,R1.x,R1.y,R1.z,R1.w}; \
        float qq[8] = {Q0.x,Q0.y,Q0.z,Q0.w,Q1.x,Q1.y,Q1.z,Q1.w}; \
        _Pragma("unroll") \
        for (int q = 0; q < 8; q++) { \
            float dr = rr[q] - pr[I][q]; \
            float di = qq[q] - pi[I][q]; \
            num += dr * dr + di * di; \
            den += rr[q] * rr[q] + qq[q] * qq[q]; } }

    LDROW(Cr0, Cr1, Cq0, Cq1, 2)
    LDROW(Dr0, Dr1, Dq0, Dq1, 3)
    CONS(Ar0, Ar1, Aq0, Aq1, 0)
    CONS(Br0, Br1, Bq0, Bq1, 1)
    LDROW(Ar0, Ar1, Aq0, Aq1, 4)
    LDROW(Br0, Br1, Bq0, Bq1, 5)
    CONS(Cr0, Cr1, Cq0, Cq1, 2)
    CONS(Dr0, Dr1, Dq0, Dq1, 3)
    LDROW(Cr0, Cr1, Cq0, Cq1, 6)
    LDROW(Dr0, Dr1, Dq0, Dq1, 7)
    CONS(Ar0, Ar1, Aq0, Aq1, 4)
    CONS(Br0, Br1, Bq0, Bq1, 5)
    CONS(Cr0, Cr1, Cq0, Cq1, 6)
    CONS(Dr0, Dr1, Dq0, Dq1, 7)

    #pragma unroll
    for (int off = 32; off > 0; off >>= 1) {
        num += __shfl_down(num, off, 64);
        den += __shfl_down(den, off, 64);
    }
    if ((t & 63) == 0) { redN[t >> 6] = num; redD[t >> 6] = den; }
    __syncthreads();
    if (t == 0) {
        int bid = ((int)blockIdx.z * 8 + (int)blockIdx.y) * 8 + (int)blockIdx.x;
        int moff = (int)gridDim.z * 2 + bid * 2;
        ws[moff]     = redN[0] + redN[1] + redN[2] + redN[3];
        ws[moff + 1] = redD[0] + redD[1] + redD[2] + redD[3];
    }
}

// ---------------- final reduce: one block sums all partials ----------------
__global__ __launch_bounds__(256) void fin_kernel(const float* __restrict__ ws,
                                                  const int* __restrict__ bsz,
                                                  float* __restrict__ out, int B) {
    __shared__ float acc[16];
    int t = threadIdx.x;
    float num = 0.f, den = 0.f, sU = 0.f, sV2 = 0.f;
    int moff = B * 2;
    int nmain = B * 64;
    for (int i = t; i < nmain; i += 256) {
        num += ws[moff + 2 * i];
        den += ws[moff + 2 * i + 1];
    }
    for (int i = t; i < B * 2; i += 256) {
        float g = ws[i];
        if (i & 1) sV2 += g; else sU += g;
    }
    #pragma unroll
    for (int off = 32; off > 0; off >>= 1) {
        num += __shfl_down(num, off, 64);
        den += __shfl_down(den, off, 64);
        sU  += __shfl_down(sU, off, 64);
        sV2 += __shfl_down(sV2, off, 64);
    }
    if ((t & 63) == 0) {
        int w = t >> 6;
        acc[w * 4 + 0] = num; acc[w * 4 + 1] = den;
        acc[w * 4 + 2] = sU;  acc[w * 4 + 3] = sV2;
    }
    __syncthreads();
    if (t == 0) {
        num = acc[0] + acc[4] + acc[8]  + acc[12];
        den = acc[1] + acc[5] + acc[9]  + acc[13];
        sU  = acc[2] + acc[6] + acc[10] + acc[14];
        sV2 = acc[3] + acc[7] + acc[11] + acc[15];
        float Bf = (float)bsz[0];
        float o1 = sU / Bf, o2 = sV2 / Bf;
        out[0] = num / den + 0.01f * (o1 + o2);
        out[1] = o1;
        out[2] = o2;
    }
}

extern "C" void kernel_launch(void* const* d_in, const int* in_sizes, int n_in,
                              void* d_out, int out_size, void* d_ws, size_t ws_size,
                              hipStream_t stream) {
    const float* nn = (const float*)d_in[0];
    const float* kr = (const float*)d_in[1];
    const float* ki = (const float*)d_in[2];
    const int* bsz = (const int*)d_in[3];
    float* ws = (float*)d_ws;
    float* out = (float*)d_out;
    int B = in_sizes[0] / SROW;

    hipLaunchKernelGGL(gram_kernel, dim3(B * 2), dim3(256), 0, stream, nn, ws);
    hipLaunchKernelGGL(main_kernel, dim3(E / 128, E / 128, B), dim3(256), 0, stream,
                       nn, kr, ki, ws);
    hipLaunchKernelGGL(fin_kernel, dim3(1), dim3(256), 0, stream, ws, bsz, out, B);
}